// Round 11
// baseline (284.356 us; speedup 1.0000x reference)
//
#include <hip/hip_runtime.h>
#include <hip/hip_bf16.h>
#include <math.h>

#define NB 2
#define LL 64
#define NMESH 100000
#define HEADS_O 8
#define DHC 64
#define DMODEL 512
#define DINNER 1024
#define DSTATE 64
#define NH 16
#define CONVDIM 1152
#define DINPROJ 2208
#define DOUT 256
#define NCHUNK 6250   // 100000 / 16, exact

typedef __attribute__((ext_vector_type(8))) short short8v;   // 8 x bf16
typedef __attribute__((ext_vector_type(4))) float f32x4;

__device__ __forceinline__ unsigned short f2bf(float f) {
  union { float f; unsigned u; } v; v.f = f;
  unsigned u = v.u;
  u += 0x7FFFu + ((u >> 16) & 1u);
  return (unsigned short)(u >> 16);
}

__device__ __forceinline__ short8v pack_bf16(float4 lo, float4 hi) {
  short8v r;
  r[0] = (short)f2bf(lo.x); r[1] = (short)f2bf(lo.y);
  r[2] = (short)f2bf(lo.z); r[3] = (short)f2bf(lo.w);
  r[4] = (short)f2bf(hi.x); r[5] = (short)f2bf(hi.y);
  r[6] = (short)f2bf(hi.z); r[7] = (short)f2bf(hi.w);
  return r;
}

__device__ __forceinline__ float dot4(float4 a, const float* b) {
  return a.x*b[0] + a.y*b[1] + a.z*b[2] + a.w*b[3];
}

__device__ __forceinline__ float silu(float s) { return s / (1.f + expf(-s)); }

// ---------------------------------------------------------------- K1: in_proj (weight-streaming)
__global__ void k_inproj(const float* __restrict__ st, const float* __restrict__ w,
                         float* __restrict__ zx) {
  int oc = blockIdx.x;             // 0..8 : o = oc*256 + t
  int blc = blockIdx.y;            // 0..31: bl = blc*4 + r
  int t = threadIdx.x;
  __shared__ float u[4][DMODEL];   // 8 KB
  for (int idx = t; idx < 4*DMODEL; idx += 256) {
    int r = idx >> 9, m = idx & 511;
    int bl = blc*4 + r; int b = bl >> 6, l = bl & 63;
    u[r][m] = st[((size_t)(b*HEADS_O + (m >> 6))*LL + l)*DHC + (m & 63)];
  }
  __syncthreads();
  int o = oc*256 + t;
  if (o < DINPROJ) {
    const float4* wr = (const float4*)(w + (size_t)o*DMODEL);
    float acc[4] = {0,0,0,0};
    for (int m4 = 0; m4 < DMODEL/4; ++m4) {
      float4 wv = wr[m4];
      #pragma unroll
      for (int r = 0; r < 4; ++r) acc[r] += dot4(wv, &u[r][m4*4]);
    }
    #pragma unroll
    for (int r = 0; r < 4; ++r)
      zx[(size_t)(blc*4 + r)*DINPROJ + o] = acc[r];
  }
}

// ---------------------------------------------------------------- K2: fused conv+silu+dt+SSD scan
// Stages the raw zx slab (x[hh], B, C channels; 64 l x 192 ch) into LDS in one
// coalesced pass, then computes the 3-tap conv+silu from LDS (cheap, conflict-
// free), then the parallel-form scan (identical math to the verified k_scan).
__global__ void k_scanF(const float* __restrict__ zx, const float* __restrict__ cw,
                        const float* __restrict__ cb, const float* __restrict__ dtb,
                        const float* __restrict__ A_log, float* __restrict__ ybuf) {
  int blk = blockIdx.x;
  int s = blk >> 4, hh = blk & 15;
  int b = s & 1;
  bool rev = (s >= 2);
  int t = threadIdx.x;
  int wv = t >> 6, lane = t & 63;
  __shared__ float zr[64][192];    // 48 KB raw zx slab
  __shared__ float Bs[64*68];
  __shared__ float Cs[64*68];
  __shared__ float Xs[64*64];
  __shared__ float dts[64];
  __shared__ float Dc[64];

  for (int idx = t; idx < 64*192; idx += 256) {
    int l = idx / 192, j = idx % 192;
    int c = (j < 64) ? (hh*64 + j) : ((j < 128) ? (1024 + j - 64) : (1088 + j - 128));
    zr[l][j] = zx[(size_t)(b*LL + l)*DINPROJ + DINNER + c];
  }
  if (t < 64) {
    int tt = rev ? (63 - t) : t;
    int ch = rev ? (16 + hh) : hh;
    float v = zx[(size_t)(b*LL + tt)*DINPROJ + (DINNER + CONVDIM) + ch] + dtb[hh];
    dts[t] = (v > 20.f) ? v : log1pf(expf(v));
  }
  __syncthreads();
  // conv + silu from LDS
  for (int id = t; id < 4096; id += 256) {
    int tt0 = id >> 6, n = id & 63;
    int tt = rev ? (63 - tt0) : tt0;
    int cx = hh*64 + n, cB = 1024 + n, cC = 1088 + n;
    float sx = cb[cx], sb = cb[cB], sc = cb[cC];
    #pragma unroll
    for (int k = 0; k < 3; ++k) {
      int l = tt - 1 + k;
      if (l >= 0 && l < 64) {
        sx += cw[cx*3 + k] * zr[l][n];
        sb += cw[cB*3 + k] * zr[l][64 + n];
        sc += cw[cC*3 + k] * zr[l][128 + n];
      }
    }
    Xs[tt0*64 + n] = silu(sx);
    Bs[tt0*68 + n] = silu(sb);
    Cs[tt0*68 + n] = silu(sc);
  }
  __syncthreads();
  if (t < 64) {
    float v = dts[t];
    #pragma unroll
    for (int m = 1; m < 64; m <<= 1) {
      float o = __shfl_up(v, m, 64);
      if (lane >= m) v += o;
    }
    Dc[t] = v;
  }
  __syncthreads();
  float A = -expf(A_log[hh]);
  float g[16];
  #pragma unroll
  for (int i = 0; i < 16; ++i) {
    int tt = wv + 4*i;
    int ta = lane;
    float gv = 0.f;
    if (ta <= tt) {
      const float* Br = &Bs[ta*68];
      const float* Cr = &Cs[tt*68];
      float dot = 0.f;
      #pragma unroll
      for (int n4 = 0; n4 < 16; ++n4) {
        float4 bv = *(const float4*)&Br[n4*4];
        float4 cv = *(const float4*)&Cr[n4*4];
        dot += bv.x*cv.x + bv.y*cv.y + bv.z*cv.z + bv.w*cv.w;
      }
      gv = dot * expf(A * (Dc[tt] - Dc[ta])) * dts[ta];
    }
    g[i] = gv;
  }
  __syncthreads();
  #pragma unroll
  for (int i = 0; i < 16; ++i) Bs[(wv + 4*i)*64 + lane] = g[i];
  __syncthreads();
  for (int id = t; id < 4096; id += 256) {
    int tt = id >> 6, p = id & 63;
    float y = 0.f;
    for (int ta = 0; ta <= tt; ++ta) y += Bs[tt*64 + ta] * Xs[ta*64 + p];
    ybuf[(size_t)(s*LL + tt)*DINNER + hh*64 + p] = y;
  }
}

// ---------------------------------------------------------------- K3: fused conv(xog) + combine + gate + RMS + out_proj + mfrag
__global__ void k_comboF(const float* __restrict__ zx, const float* __restrict__ cw,
                         const float* __restrict__ cb, const float* __restrict__ yb,
                         const float* __restrict__ fcD, const float* __restrict__ Dd,
                         const float* __restrict__ nw, const float* __restrict__ opw,
                         const float* __restrict__ tow, unsigned short* __restrict__ mfp) {
  int bl = blockIdx.x; int b = bl >> 6, l = bl & 63;
  int t = threadIdx.x;
  __shared__ float zs[3][DINNER];  // rows l-1,l,l+1 of x-channels, 12 KB
  __shared__ float xog[DINNER];
  __shared__ float yrow[DINNER];
  __shared__ float ohs[DMODEL];
  __shared__ float diag[NH];
  __shared__ float wsum[4];
  for (int idx = t; idx < 3*DINNER; idx += 256) {
    int r = idx >> 10, c = idx & 1023;
    int ll = l - 1 + r;
    zs[r][c] = (ll >= 0 && ll < LL) ? zx[(size_t)(b*LL + ll)*DINPROJ + DINNER + c] : 0.f;
  }
  __syncthreads();
  #pragma unroll
  for (int i = 0; i < 4; ++i) {
    int c = t + 256*i;
    float s = cb[c] + cw[c*3]*zs[0][c] + cw[c*3+1]*zs[1][c] + cw[c*3+2]*zs[2][c];
    xog[c] = silu(s);
  }
  __syncthreads();
  {
    int hh = t >> 4, j = t & 15;
    const float* fr = fcD + (size_t)hh*DINNER;
    float acc = 0.f;
    for (int k = 0; k < 64; ++k) acc += xog[j + 16*k] * fr[j + 16*k];
    #pragma unroll
    for (int m = 8; m >= 1; m >>= 1) acc += __shfl_xor(acc, m, 64);
    if (j == 0) diag[hh] = acc + Dd[hh];
  }
  __syncthreads();
  float ss = 0.f;
  float y2v[4];
  #pragma unroll
  for (int i = 0; i < 4; ++i) {
    int c = t + 256*i;
    float yf = (l == 0)  ? 0.f : yb[(size_t)(b*LL + l - 1)*DINNER + c];
    float yw = (l == 63) ? 0.f : yb[(size_t)((2+b)*LL + 62 - l)*DINNER + c];
    float y1 = yf + yw + xog[c]*diag[c >> 6];
    float z = zx[(size_t)bl*DINPROJ + c];
    float y2 = y1 * silu(z);
    y2v[i] = y2;
    ss += y2*y2;
  }
  #pragma unroll
  for (int m = 32; m >= 1; m >>= 1) ss += __shfl_xor(ss, m, 64);
  if ((t & 63) == 0) wsum[t >> 6] = ss;
  __syncthreads();
  float tot = wsum[0] + wsum[1] + wsum[2] + wsum[3];
  float scale = rsqrtf(tot * (1.f/1024.f) + 1e-5f);
  #pragma unroll
  for (int i = 0; i < 4; ++i) {
    int c = t + 256*i;
    yrow[c] = y2v[i] * scale * nw[c];
  }
  __syncthreads();
  // out_proj: 512 outs, 2 per thread
  #pragma unroll
  for (int oi = 0; oi < 2; ++oi) {
    int o = t + 256*oi;
    const float4* wr = (const float4*)(opw + (size_t)o*DINNER);
    float acc = 0.f;
    #pragma unroll 4
    for (int k4 = 0; k4 < DINNER/4; ++k4) acc += dot4(wr[k4], &yrow[k4*4]);
    ohs[o] = acc;
  }
  __syncthreads();
  // mfrag: M[b,h,g,d] = sum_c ohs[h*64+c]*tow[d,h*64+c]; this block owns g = l
  int g = l;
  int kkq = g >> 5;
  int lnhi = ((g & 31) >> 3) << 4;
  int j = g & 7;
  #pragma unroll
  for (int ii = 0; ii < 8; ++ii) {
    int idx = t + 256*ii;            // (h,d)
    int h = idx >> 8, d = idx & 255;
    const float4* wr = (const float4*)(tow + (size_t)d*DMODEL + h*64);
    const float* op = &ohs[h*64];
    float acc = 0.f;
    #pragma unroll
    for (int c4 = 0; c4 < 16; ++c4) acc += dot4(wr[c4], &op[c4*4]);
    int ln = (d & 15) | lnhi;
    mfp[((((size_t)(b*HEADS_O + h)*2 + kkq)*16 + (d >> 4))*64 + ln)*8 + j] = f2bf(acc);
  }
}

// ---------------------------------------------------------------- K4: amplification-1x GEMM, 2-chunk-deep pipeline
// out[b,n,d] = sum_{h,g} W[b,h,n,g]*M[b,h,g,d] + tob[d]
// 256 blocks x 512 thr (8 waves), 1 block/CU. As round 10 (convert-once bf16
// A-share, B in regs, W crosses fabric once) but the register staging is TWO
// chunks deep: two named reg sets alternate; ALOAD(c+256) is issued this
// iteration while AWRITE consumes the set loaded LAST iteration -> a full
// ~4700cy in-flight window instead of ~600cy. Per-chunk barrier is
// lgkmcnt(0)+s_barrier only (stores & prefetch loads stay outstanding).
__global__ __launch_bounds__(512, 1) void k_out_gemm(const float* __restrict__ W,
                                                     const unsigned short* __restrict__ mf,
                                                     const float* __restrict__ tob,
                                                     float* __restrict__ out) {
  int bx = blockIdx.x;
  int b    = bx >> 7;
  int base = bx & 127;
  int tid = threadIdx.x;
  int wv = tid >> 6, lane = tid & 63;
  int r16 = lane & 15, kg = lane >> 4;

  __shared__ __align__(16) unsigned short lsA[2][16][512];  // 32 KB bf16 dbuf

  // ---- B fragments into registers: wave wv owns ct = 2wv, 2wv+1
  short8v B0[16], B1[16];
  {
    const unsigned short* mfb = mf + (size_t)b*(16*16*512) + lane*8;
    #pragma unroll
    for (int ks = 0; ks < 16; ++ks) {
      B0[ks] = *(const short8v*)(mfb + ((size_t)ks*16 + 2*wv    )*512);
      B1[ks] = *(const short8v*)(mfb + ((size_t)ks*16 + 2*wv + 1)*512);
    }
  }
  float bias0 = tob[wv*32 + r16];
  float bias1 = tob[wv*32 + 16 + r16];

  const float* wbase = W + ((size_t)(b*HEADS_O + wv)*NMESH + r16)*64 + kg*8;

  float4 a0, a1, a2, a3;   // reg set A
  float4 b0, b1, b2, b3;   // reg set B

  #define ALOADS(cc, v0, v1, v2, v3) do { \
    const float* p0 = wbase + (size_t)(cc)*1024; \
    v0 = *(const float4*)p0;        v1 = *(const float4*)(p0 + 4); \
    v2 = *(const float4*)(p0 + 32); v3 = *(const float4*)(p0 + 36); \
  } while (0)
  #define AWR(pp, v0, v1, v2, v3) do { \
    *(short8v*)&lsA[pp][2*wv    ][lane*8] = pack_bf16(v0, v1); \
    *(short8v*)&lsA[pp][2*wv + 1][lane*8] = pack_bf16(v2, v3); \
  } while (0)
  #define MFMA_STORE(pp, cc) do { \
    f32x4 acc0 = (f32x4){0.f,0.f,0.f,0.f}; \
    f32x4 acc1 = (f32x4){0.f,0.f,0.f,0.f}; \
    _Pragma("unroll") \
    for (int ks = 0; ks < 16; ++ks) { \
      short8v af = *(const short8v*)&lsA[pp][ks][lane*8]; \
      acc0 = __builtin_amdgcn_mfma_f32_16x16x32_bf16(af, B0[ks], acc0, 0, 0, 0); \
      acc1 = __builtin_amdgcn_mfma_f32_16x16x32_bf16(af, B1[ks], acc1, 0, 0, 0); \
    } \
    int rb = (cc)*16 + kg*4; \
    int cg = wv*32 + r16; \
    _Pragma("unroll") \
    for (int r = 0; r < 4; ++r) { \
      out[((size_t)b*NMESH + rb + r)*DOUT + cg]      = acc0[r] + bias0; \
      out[((size_t)b*NMESH + rb + r)*DOUT + cg + 16] = acc1[r] + bias1; \
    } \
  } while (0)
  #define KBAR() do { \
    asm volatile("s_waitcnt lgkmcnt(0)" ::: "memory"); \
    __builtin_amdgcn_sched_barrier(0); \
    __builtin_amdgcn_s_barrier(); \
    __builtin_amdgcn_sched_barrier(0); \
  } while (0)

  // ---- prologue: ls[0] <- chunk base (via set A); set B <- chunk base+128
  ALOADS(base, a0, a1, a2, a3);
  AWR(0, a0, a1, a2, a3);
  ALOADS(base + 128, b0, b1, b2, b3);   // always valid: base+128 < 6250
  KBAR();

  int c = base;
  int p = 0;
  for (;;) {
    // ---- half A: process chunk c from ls[p]; prefetch c+256 into set A
    if (c + 256 < NCHUNK) ALOADS(c + 256, a0, a1, a2, a3);
    __builtin_amdgcn_sched_barrier(0);
    MFMA_STORE(p, c);
    if (c + 128 >= NCHUNK) break;
    __builtin_amdgcn_sched_barrier(0);
    AWR(p ^ 1, b0, b1, b2, b3);         // set B = chunk c+128, loaded 1 iter ago
    KBAR();
    p ^= 1; c += 128;
    // ---- half B: process chunk c from ls[p]; prefetch c+256 into set B
    if (c + 256 < NCHUNK) ALOADS(c + 256, b0, b1, b2, b3);
    __builtin_amdgcn_sched_barrier(0);
    MFMA_STORE(p, c);
    if (c + 128 >= NCHUNK) break;
    __builtin_amdgcn_sched_barrier(0);
    AWR(p ^ 1, a0, a1, a2, a3);         // set A = chunk c+128, loaded 1 iter ago
    KBAR();
    p ^= 1; c += 128;
  }
  #undef ALOADS
  #undef AWR
  #undef MFMA_STORE
  #undef KBAR
}

// ----------------------------------------------------------------
extern "C" void kernel_launch(void* const* d_in, const int* in_sizes, int n_in,
                              void* d_out, int out_size, void* d_ws, size_t ws_size,
                              hipStream_t stream) {
  (void)in_sizes; (void)n_in; (void)out_size; (void)ws_size;
  const float* st   = (const float*)d_in[0];
  const float* sw   = (const float*)d_in[1];
  const float* ipw  = (const float*)d_in[2];
  const float* cw   = (const float*)d_in[3];
  const float* cb   = (const float*)d_in[4];
  const float* dtb  = (const float*)d_in[5];
  const float* alog = (const float*)d_in[6];
  const float* fcD  = (const float*)d_in[7];
  const float* Dd   = (const float*)d_in[8];
  const float* nw   = (const float*)d_in[9];
  const float* opw  = (const float*)d_in[10];
  const float* tow  = (const float*)d_in[11];
  const float* tob  = (const float*)d_in[12];
  float* out = (float*)d_out;
  unsigned char* ws = (unsigned char*)d_ws;

  float* zx = (float*)(ws + 0);                          // 2*64*2208*4 = 1130496
  float* yb = (float*)(ws + 1130496);                    // 4*64*1024*4 = 1048576
  unsigned short* mfr = (unsigned short*)(ws + 2179072); // 524288

  k_inproj  <<<dim3(9, 32), 256, 0, stream>>>(st, ipw, zx);
  k_scanF   <<<64,  256, 0, stream>>>(zx, cw, cb, dtb, alog, yb);
  k_comboF  <<<128, 256, 0, stream>>>(zx, cw, cb, yb, fcD, Dd, nw, opw, tow, mfr);
  k_out_gemm<<<256, 512, 0, stream>>>(sw, mfr, tob, out);
}

// Round 12
// 241.787 us; speedup vs baseline: 1.1761x; 1.1761x over previous
//
#include <hip/hip_runtime.h>
#include <hip/hip_bf16.h>
#include <math.h>

#define NB 2
#define LL 64
#define NMESH 100000
#define HEADS_O 8
#define DHC 64
#define DMODEL 512
#define DINNER 1024
#define DSTATE 64
#define NH 16
#define CONVDIM 1152
#define DINPROJ 2208
#define DOUT 256
#define NCHUNK 6250   // 100000 / 16, exact

typedef __attribute__((ext_vector_type(8))) short short8v;   // 8 x bf16
typedef __attribute__((ext_vector_type(4))) float f32x4;

__device__ __forceinline__ unsigned short f2bf(float f) {
  union { float f; unsigned u; } v; v.f = f;
  unsigned u = v.u;
  u += 0x7FFFu + ((u >> 16) & 1u);
  return (unsigned short)(u >> 16);
}

__device__ __forceinline__ short8v pack_bf16(float4 lo, float4 hi) {
  short8v r;
  r[0] = (short)f2bf(lo.x); r[1] = (short)f2bf(lo.y);
  r[2] = (short)f2bf(lo.z); r[3] = (short)f2bf(lo.w);
  r[4] = (short)f2bf(hi.x); r[5] = (short)f2bf(hi.y);
  r[6] = (short)f2bf(hi.z); r[7] = (short)f2bf(hi.w);
  return r;
}

__device__ __forceinline__ float dot4(float4 a, const float* b) {
  return a.x*b[0] + a.y*b[1] + a.z*b[2] + a.w*b[3];
}

__device__ __forceinline__ float silu(float s) { return s / (1.f + expf(-s)); }

// ---------------------------------------------------------------- K1: in_proj (weight-streaming)
__global__ void k_inproj(const float* __restrict__ st, const float* __restrict__ w,
                         float* __restrict__ zx) {
  int oc = blockIdx.x;             // 0..8 : o = oc*256 + t
  int blc = blockIdx.y;            // 0..15: bl = blc*8 + r
  int t = threadIdx.x;
  __shared__ float u[8][DMODEL];   // 16 KB
  for (int idx = t; idx < 8*DMODEL; idx += 256) {
    int r = idx >> 9, m = idx & 511;
    int bl = blc*8 + r; int b = bl >> 6, l = bl & 63;
    u[r][m] = st[((size_t)(b*HEADS_O + (m >> 6))*LL + l)*DHC + (m & 63)];
  }
  __syncthreads();
  int o = oc*256 + t;
  if (o < DINPROJ) {
    const float4* wr = (const float4*)(w + (size_t)o*DMODEL);
    float acc[8] = {0,0,0,0,0,0,0,0};
    for (int m4 = 0; m4 < DMODEL/4; ++m4) {
      float4 wv = wr[m4];
      #pragma unroll
      for (int r = 0; r < 8; ++r) acc[r] += dot4(wv, &u[r][m4*4]);
    }
    #pragma unroll
    for (int r = 0; r < 8; ++r)
      zx[(size_t)(blc*8 + r)*DINPROJ + o] = acc[r];
  }
}

// ---------------------------------------------------------------- K2: fused conv+silu AND dt softplus
__global__ void k_convdt(const float* __restrict__ zx, const float* __restrict__ cw,
                         const float* __restrict__ cb, const float* __restrict__ dtb,
                         float* __restrict__ conv_out, float* __restrict__ dtbuf) {
  if (blockIdx.x < 576) {
    int i = blockIdx.x*256 + threadIdx.x;           // < 147456
    int c = i % CONVDIM; int l = (i / CONVDIM) % LL; int b = i / (CONVDIM*LL);
    float s = cb[c];
    #pragma unroll
    for (int k = 0; k < 3; ++k) {
      int tt = l - 1 + k;
      if (tt >= 0 && tt < LL)
        s += cw[c*3 + k] * zx[(size_t)(b*LL + tt)*DINPROJ + DINNER + c];
    }
    conv_out[i] = silu(s);
  } else {
    int i = (blockIdx.x - 576)*256 + threadIdx.x;   // (s*64+l)*16+h, 4096 total
    if (i < 4*LL*NH) {
      int h = i & 15, l = (i >> 4) & 63, s = i >> 10;
      float v;
      if (s < 2)
        v = zx[(size_t)(s*LL + l)*DINPROJ + (DINNER + CONVDIM) + h];
      else
        v = zx[(size_t)((s-2)*LL + (63-l))*DINPROJ + (DINNER + CONVDIM) + 16 + h];
      v += dtb[h];
      dtbuf[i] = (v > 20.f) ? v : log1pf(expf(v));
    }
  }
}

// ---------------------------------------------------------------- K3: SSD scan (parallel form)
__global__ void k_scan(const float* __restrict__ conv_out, const float* __restrict__ dtbuf,
                       const float* __restrict__ A_log, float* __restrict__ ybuf) {
  int blk = blockIdx.x;
  int s = blk >> 4, hh = blk & 15;
  int b = s & 1;
  bool rev = (s >= 2);
  int t = threadIdx.x;
  int wv = t >> 6, lane = t & 63;
  __shared__ float Bs[64*68];
  __shared__ float Cs[64*68];
  __shared__ float Xs[64*64];
  __shared__ float dts[64];
  __shared__ float Dc[64];

  for (int id = t; id < 4096; id += 256) {
    int tt0 = id >> 6, n = id & 63;
    int tt = rev ? (63 - tt0) : tt0;
    size_t base = (size_t)(b*LL + tt) * CONVDIM;
    Xs[tt0*64 + n] = conv_out[base + hh*64 + n];
    Bs[tt0*68 + n] = conv_out[base + DINNER + n];
    Cs[tt0*68 + n] = conv_out[base + DINNER + DSTATE + n];
  }
  if (t < 64) dts[t] = dtbuf[(size_t)(s*LL + t)*NH + hh];
  __syncthreads();
  if (t < 64) {
    float v = dts[t];
    #pragma unroll
    for (int m = 1; m < 64; m <<= 1) {
      float o = __shfl_up(v, m, 64);
      if (lane >= m) v += o;
    }
    Dc[t] = v;
  }
  __syncthreads();
  float A = -expf(A_log[hh]);
  float g[16];
  #pragma unroll
  for (int i = 0; i < 16; ++i) {
    int tt = wv + 4*i;
    int ta = lane;
    float gv = 0.f;
    if (ta <= tt) {
      const float* Br = &Bs[ta*68];
      const float* Cr = &Cs[tt*68];
      float dot = 0.f;
      #pragma unroll
      for (int n4 = 0; n4 < 16; ++n4) {
        float4 bv = *(const float4*)&Br[n4*4];
        float4 cv = *(const float4*)&Cr[n4*4];
        dot += bv.x*cv.x + bv.y*cv.y + bv.z*cv.z + bv.w*cv.w;
      }
      gv = dot * expf(A * (Dc[tt] - Dc[ta])) * dts[ta];
    }
    g[i] = gv;
  }
  __syncthreads();
  #pragma unroll
  for (int i = 0; i < 16; ++i) Bs[(wv + 4*i)*64 + lane] = g[i];
  __syncthreads();
  for (int id = t; id < 4096; id += 256) {
    int tt = id >> 6, p = id & 63;
    float y = 0.f;
    for (int ta = 0; ta <= tt; ++ta) y += Bs[tt*64 + ta] * Xs[ta*64 + p];
    ybuf[(size_t)(s*LL + tt)*DINNER + hh*64 + p] = y;
  }
}

// ---------------------------------------------------------------- K4: combine + gate + RMSnorm -> ynorm
__global__ void k_norm(const float* __restrict__ conv_out, const float* __restrict__ zx,
                       const float* __restrict__ yb, const float* __restrict__ fcD,
                       const float* __restrict__ Dd, const float* __restrict__ nw,
                       float* __restrict__ ynorm) {
  int bl = blockIdx.x; int b = bl >> 6, l = bl & 63;
  int t = threadIdx.x;
  __shared__ float xog[DINNER];
  __shared__ float diag[NH];
  __shared__ float wsum[4];
  size_t base = (size_t)bl * CONVDIM;
  for (int c = t; c < DINNER; c += 256) xog[c] = conv_out[base + c];
  __syncthreads();
  {
    int hh = t >> 4, j = t & 15;
    const float* fr = fcD + (size_t)hh*DINNER;
    float acc = 0.f;
    for (int k = 0; k < 64; ++k) acc += xog[j + 16*k] * fr[j + 16*k];
    #pragma unroll
    for (int m = 8; m >= 1; m >>= 1) acc += __shfl_xor(acc, m, 64);
    if (j == 0) diag[hh] = acc + Dd[hh];
  }
  __syncthreads();
  float ss = 0.f;
  float y2v[4];
  #pragma unroll
  for (int i = 0; i < 4; ++i) {
    int c = t + 256*i;
    float yf = (l == 0)  ? 0.f : yb[(size_t)(b*LL + l - 1)*DINNER + c];
    float yw = (l == 63) ? 0.f : yb[(size_t)((2+b)*LL + 62 - l)*DINNER + c];
    float y1 = yf + yw + xog[c]*diag[c >> 6];
    float z = zx[(size_t)bl*DINPROJ + c];
    float y2 = y1 * silu(z);
    y2v[i] = y2;
    ss += y2*y2;
  }
  #pragma unroll
  for (int m = 32; m >= 1; m >>= 1) ss += __shfl_xor(ss, m, 64);
  if ((t & 63) == 0) wsum[t >> 6] = ss;
  __syncthreads();
  float tot = wsum[0] + wsum[1] + wsum[2] + wsum[3];
  float scale = rsqrtf(tot * (1.f/1024.f) + 1e-5f);
  #pragma unroll
  for (int i = 0; i < 4; ++i) {
    int c = t + 256*i;
    ynorm[(size_t)bl*DINNER + c] = y2v[i] * scale * nw[c];
  }
}

// ---------------------------------------------------------------- K5: out_proj (weight-streaming)
__global__ void k_oproj(const float* __restrict__ ynorm, const float* __restrict__ opw,
                        float* __restrict__ oh) {
  int oc = blockIdx.x;            // 0..1 : o = oc*256 + t
  int blc = blockIdx.y;           // 0..31: bl = blc*4 + r
  int t = threadIdx.x;
  __shared__ float yr[4][DINNER]; // 16 KB
  for (int idx = t; idx < 4*DINNER; idx += 256) {
    int r = idx >> 10, k = idx & 1023;
    yr[r][k] = ynorm[(size_t)(blc*4 + r)*DINNER + k];
  }
  __syncthreads();
  int o = oc*256 + t;
  const float4* wr = (const float4*)(opw + (size_t)o*DINNER);
  float acc[4] = {0,0,0,0};
  for (int k4 = 0; k4 < DINNER/4; ++k4) {
    float4 wv = wr[k4];
    #pragma unroll
    for (int r = 0; r < 4; ++r) acc[r] += dot4(wv, &yr[r][k4*4]);
  }
  #pragma unroll
  for (int r = 0; r < 4; ++r)
    oh[(size_t)(blc*4 + r)*DMODEL + o] = acc[r];
}

// ---------------------------------------------------------------- K6: build M in B-fragment order (bf16)
__global__ void k_mfrag(const float* __restrict__ oh, const float* __restrict__ tow,
                        unsigned short* __restrict__ mfp) {
  int bgc = blockIdx.x;            // 0..15, bg = bgc*8 + r
  int dc  = blockIdx.y;            // 0..3 : d = dc*64 + dl
  int t = threadIdx.x;
  __shared__ float orow[8][DMODEL]; // 16 KB
  for (int idx = t; idx < 8*DMODEL; idx += 256) {
    int r = idx >> 9, m = idx & 511;
    orow[r][m] = oh[(size_t)(bgc*8 + r)*DMODEL + m];
  }
  __syncthreads();
  #pragma unroll
  for (int ii = 0; ii < 2; ++ii) {
    int idx = t + 256*ii;          // 0..511 -> (h, dl)
    int h = idx >> 6, dl = idx & 63;
    int d = dc*64 + dl;
    const float4* wr = (const float4*)(tow + (size_t)d*DMODEL + h*64);
    float acc[8] = {0,0,0,0,0,0,0,0};
    #pragma unroll
    for (int c4 = 0; c4 < 16; ++c4) {
      float4 wv = wr[c4];
      #pragma unroll
      for (int r = 0; r < 8; ++r) acc[r] += dot4(wv, &orow[r][h*64 + c4*4]);
    }
    #pragma unroll
    for (int r = 0; r < 8; ++r) {
      int bg = bgc*8 + r; int b = bg >> 6, g = bg & 63;
      int kk = g >> 5;
      int ln = (d & 15) | (((g & 31) >> 3) << 4);
      int j = g & 7;
      mfp[((((size_t)(b*HEADS_O + h)*2 + kk)*16 + (d >> 4))*64 + ln)*8 + j] = f2bf(acc[r]);
    }
  }
}

// ---------------------------------------------------------------- K7: amplification-1x GEMM, 2-chunk-deep pipeline
// Single-variable change vs the 241.9us round-10 baseline: register staging
// is TWO chunks deep (two named reg sets alternate; ALOAD(c+256) issued this
// iteration, AWR consumes the set loaded LAST iteration -> full-iteration
// in-flight window). Everything else identical to round 10.
__global__ __launch_bounds__(512, 1) void k_out_gemm(const float* __restrict__ W,
                                                     const unsigned short* __restrict__ mf,
                                                     const float* __restrict__ tob,
                                                     float* __restrict__ out) {
  int bx = blockIdx.x;
  int b    = bx >> 7;
  int base = bx & 127;
  int tid = threadIdx.x;
  int wv = tid >> 6, lane = tid & 63;
  int r16 = lane & 15, kg = lane >> 4;

  __shared__ __align__(16) unsigned short lsA[2][16][512];  // 32 KB bf16 dbuf

  // ---- B fragments into registers: wave wv owns ct = 2wv, 2wv+1
  short8v B0[16], B1[16];
  {
    const unsigned short* mfb = mf + (size_t)b*(16*16*512) + lane*8;
    #pragma unroll
    for (int ks = 0; ks < 16; ++ks) {
      B0[ks] = *(const short8v*)(mfb + ((size_t)ks*16 + 2*wv    )*512);
      B1[ks] = *(const short8v*)(mfb + ((size_t)ks*16 + 2*wv + 1)*512);
    }
  }
  float bias0 = tob[wv*32 + r16];
  float bias1 = tob[wv*32 + 16 + r16];

  const float* wbase = W + ((size_t)(b*HEADS_O + wv)*NMESH + r16)*64 + kg*8;

  float4 a0, a1, a2, a3;   // reg set A
  float4 b0, b1, b2, b3;   // reg set B

  #define ALOADS(cc, v0, v1, v2, v3) do { \
    const float* p0 = wbase + (size_t)(cc)*1024; \
    v0 = *(const float4*)p0;        v1 = *(const float4*)(p0 + 4); \
    v2 = *(const float4*)(p0 + 32); v3 = *(const float4*)(p0 + 36); \
  } while (0)
  #define AWR(pp, v0, v1, v2, v3) do { \
    *(short8v*)&lsA[pp][2*wv    ][lane*8] = pack_bf16(v0, v1); \
    *(short8v*)&lsA[pp][2*wv + 1][lane*8] = pack_bf16(v2, v3); \
  } while (0)
  #define MFMA_STORE(pp, cc) do { \
    f32x4 acc0 = (f32x4){0.f,0.f,0.f,0.f}; \
    f32x4 acc1 = (f32x4){0.f,0.f,0.f,0.f}; \
    _Pragma("unroll") \
    for (int ks = 0; ks < 16; ++ks) { \
      short8v af = *(const short8v*)&lsA[pp][ks][lane*8]; \
      acc0 = __builtin_amdgcn_mfma_f32_16x16x32_bf16(af, B0[ks], acc0, 0, 0, 0); \
      acc1 = __builtin_amdgcn_mfma_f32_16x16x32_bf16(af, B1[ks], acc1, 0, 0, 0); \
    } \
    int rb = (cc)*16 + kg*4; \
    int cg = wv*32 + r16; \
    _Pragma("unroll") \
    for (int r = 0; r < 4; ++r) { \
      out[((size_t)b*NMESH + rb + r)*DOUT + cg]      = acc0[r] + bias0; \
      out[((size_t)b*NMESH + rb + r)*DOUT + cg + 16] = acc1[r] + bias1; \
    } \
  } while (0)
  #define KBAR() do { \
    asm volatile("s_waitcnt lgkmcnt(0)" ::: "memory"); \
    __builtin_amdgcn_sched_barrier(0); \
    __builtin_amdgcn_s_barrier(); \
    __builtin_amdgcn_sched_barrier(0); \
  } while (0)

  // ---- prologue: ls[0] <- chunk base (via set A); set B <- chunk base+128
  ALOADS(base, a0, a1, a2, a3);
  AWR(0, a0, a1, a2, a3);
  ALOADS(base + 128, b0, b1, b2, b3);   // always valid: base+128 < 6250
  KBAR();

  int c = base;
  int p = 0;
  for (;;) {
    // ---- half A: process chunk c from ls[p]; prefetch c+256 into set A
    if (c + 256 < NCHUNK) ALOADS(c + 256, a0, a1, a2, a3);
    __builtin_amdgcn_sched_barrier(0);
    MFMA_STORE(p, c);
    if (c + 128 >= NCHUNK) break;
    __builtin_amdgcn_sched_barrier(0);
    AWR(p ^ 1, b0, b1, b2, b3);         // set B = chunk c+128, loaded 1 iter ago
    KBAR();
    p ^= 1; c += 128;
    // ---- half B: process chunk c from ls[p]; prefetch c+256 into set B
    if (c + 256 < NCHUNK) ALOADS(c + 256, b0, b1, b2, b3);
    __builtin_amdgcn_sched_barrier(0);
    MFMA_STORE(p, c);
    if (c + 128 >= NCHUNK) break;
    __builtin_amdgcn_sched_barrier(0);
    AWR(p ^ 1, a0, a1, a2, a3);         // set A = chunk c+128, loaded 1 iter ago
    KBAR();
    p ^= 1; c += 128;
  }
  #undef ALOADS
  #undef AWR
  #undef MFMA_STORE
  #undef KBAR
}

// ----------------------------------------------------------------
extern "C" void kernel_launch(void* const* d_in, const int* in_sizes, int n_in,
                              void* d_out, int out_size, void* d_ws, size_t ws_size,
                              hipStream_t stream) {
  (void)in_sizes; (void)n_in; (void)out_size; (void)ws_size;
  const float* st   = (const float*)d_in[0];
  const float* sw   = (const float*)d_in[1];
  const float* ipw  = (const float*)d_in[2];
  const float* cw   = (const float*)d_in[3];
  const float* cb   = (const float*)d_in[4];
  const float* dtb  = (const float*)d_in[5];
  const float* alog = (const float*)d_in[6];
  const float* fcD  = (const float*)d_in[7];
  const float* Dd   = (const float*)d_in[8];
  const float* nw   = (const float*)d_in[9];
  const float* opw  = (const float*)d_in[10];
  const float* tow  = (const float*)d_in[11];
  const float* tob  = (const float*)d_in[12];
  float* out = (float*)d_out;
  unsigned char* ws = (unsigned char*)d_ws;

  float* zx   = (float*)(ws + 0);            // 2*64*2208*4 = 1130496
  float* conv = (float*)(ws + 1130496);      // 2*64*1152*4 = 589824
  float* dtp  = (float*)(ws + 1720320);      // 4*64*16*4   = 16384
  float* yb   = (float*)(ws + 1736704);      // 4*64*1024*4 = 1048576
  float* ynm  = (float*)(ws + 2785280);      // 2*64*1024*4 = 524288
  float* oh   = (float*)(ws + 3309568);      // 2*64*512*4  = 262144
  unsigned short* mfr = (unsigned short*)(ws + 3571712);  // 524288

  k_inproj  <<<dim3(9, 16), 256, 0, stream>>>(st, ipw, zx);
  k_convdt  <<<592, 256, 0, stream>>>(zx, cw, cb, dtb, conv, dtp);
  k_scan    <<<64,  256, 0, stream>>>(conv, dtp, alog, yb);
  k_norm    <<<128, 256, 0, stream>>>(conv, zx, yb, fcD, Dd, nw, ynm);
  k_oproj   <<<dim3(2, 32), 256, 0, stream>>>(ynm, opw, oh);
  k_mfrag   <<<dim3(16, 4), 256, 0, stream>>>(oh, tow, mfr);
  k_out_gemm<<<256, 512, 0, stream>>>(sw, mfr, tob, out);
}